// Round 9
// baseline (266.622 us; speedup 1.0000x reference)
//
#include <hip/hip_runtime.h>
#include <hip/hip_bf16.h>

typedef __bf16 bf16_t;
typedef short  s4    __attribute__((ext_vector_type(4)));
typedef short  s8    __attribute__((ext_vector_type(8)));
typedef float  f32x4 __attribute__((ext_vector_type(4)));

#define TPW   16                     // tiles per wave
#define WAVES 4
#define ROWS_PER_BLOCK (WAVES * TPW * 16)   // 1024 -> grid = 1024 = 4 blocks/CU

__device__ __forceinline__ short bfs(float f) {
    return __builtin_bit_cast(short, (bf16_t)f);
}
__device__ __forceinline__ s4 pack4(f32x4 a) {
    s4 r; r[0]=bfs(a[0]); r[1]=bfs(a[1]); r[2]=bfs(a[2]); r[3]=bfs(a[3]); return r;
}
__device__ __forceinline__ s4 relu_pack4(f32x4 a) {
    s4 r;
    r[0]=bfs(fmaxf(a[0],0.f)); r[1]=bfs(fmaxf(a[1],0.f));
    r[2]=bfs(fmaxf(a[2],0.f)); r[3]=bfs(fmaxf(a[3],0.f));
    return r;
}
__device__ __forceinline__ s8 cat(s4 a, s4 b) {
    return __builtin_shufflevector(a, b, 0, 1, 2, 3, 4, 5, 6, 7);
}
// Native gfx950 shape: D = A*B + C, 16x16x32 bf16. k-map agnostic fragment
// construction (A and B gathered with the same per-(lane-group, elem) k order);
// C/D layout: col=lane&15, row=4*(lane>>4)+reg => a layer's D regs are exactly
// the next layer's B regs (after relu+pack+cat).
#define MFMA32(a,b,c) __builtin_amdgcn_mfma_f32_16x16x32_bf16(a, b, c, 0, 0, 0)
#define PRIO_HI() __builtin_amdgcn_s_setprio(1)
#define PRIO_LO() __builtin_amdgcn_s_setprio(0)

// Design ledger (measured):
//  - r1/r6: min-waves __launch_bounds__ caps -> allocator spills catastrophically. Never cap.
//  - r4: 2-tile intra-wave ILP: neutral. r8: VGPR diet to 92 (5-wave tier): no gain,
//    LDS weight readback in the chain costs ~8us. => all-reg weights, single tile chain.
//  - r7: dropping input prefetch costs ~10us. Keep the rotation.
//  - NEW (r9): waves of a block are phase-locked (same code, same start, no barriers)
//    -> both pipes <50% busy. Stagger each wave's tile order by 4 (wave-uniform SGPR
//    math, ~0 VGPR) so the 4 waves occupy different layers at any instant, and raise
//    wave priority inside MFMA clusters so MFMA-phase waves win issue arbitration.
__global__ __launch_bounds__(256) void nerf_fused(
    const float* __restrict__ pos, const float* __restrict__ dir,
    const float* __restrict__ W1, const float* __restrict__ b1,
    const float* __restrict__ W2, const float* __restrict__ b2,
    const float* __restrict__ W3, const float* __restrict__ b3,
    const float* __restrict__ W4, const float* __restrict__ b4,
    const float* __restrict__ W5, const float* __restrict__ b5,
    float* __restrict__ outD, float* __restrict__ outC)
{
    const int tid  = threadIdx.x;
    const int w    = tid >> 6;
    const int lane = tid & 63;
    const int q    = lane >> 4;    // lane-group 0..3
    const int n    = lane & 15;    // A row / B col / sample-within-tile

    // ---------- weight A-fragments (s8 = concat of two 16-k subtiles) ----------
    s8 wa1[4], wa2x[2], wa3[4], wa4x[4][2], wa5x[2];
    #pragma unroll
    for (int t = 0; t < 4; ++t)
        #pragma unroll
        for (int h = 0; h < 2; ++h)
            #pragma unroll
            for (int i = 0; i < 4; ++i)
                wa1[t][4*h+i] = bfs(W1[(16*h + 4*q + i) * 64 + 16*t + n]);      // [32,64]
    #pragma unroll
    for (int j = 0; j < 2; ++j)
        #pragma unroll
        for (int h = 0; h < 2; ++h)
            #pragma unroll
            for (int i = 0; i < 4; ++i)
                wa2x[j][4*h+i] = bfs(W2[(16*(2*j+h) + 4*q + i) * 16 + n]);      // [64,16]
    #pragma unroll
    for (int t = 0; t < 4; ++t)
        #pragma unroll
        for (int h = 0; h < 2; ++h)
            #pragma unroll
            for (int i = 0; i < 4; ++i)
                wa3[t][4*h+i] = bfs(W3[(16*h + 4*q + i) * 64 + 16*t + n]);      // [32,64]
    #pragma unroll
    for (int t = 0; t < 4; ++t)
        #pragma unroll
        for (int j = 0; j < 2; ++j)
            #pragma unroll
            for (int h = 0; h < 2; ++h)
                #pragma unroll
                for (int i = 0; i < 4; ++i)
                    wa4x[t][j][4*h+i] = bfs(W4[(16*(2*j+h) + 4*q + i) * 64 + 16*t + n]); // [64,64]
    #pragma unroll
    for (int j = 0; j < 2; ++j)
        #pragma unroll
        for (int h = 0; h < 2; ++h)
            #pragma unroll
            for (int i = 0; i < 4; ++i)
                wa5x[j][4*h+i] = (n < 3) ? bfs(W5[(16*(2*j+h) + 4*q + i) * 3 + n])
                                         : (short)0;                             // [64,3] pad

    // ---------- bias C-initializers (channel index = 4q+r within tile t) ----------
    f32x4 bi1[4], bi3[4], bi4[4], bi2, bi5;
    #pragma unroll
    for (int t = 0; t < 4; ++t)
        #pragma unroll
        for (int r = 0; r < 4; ++r) {
            bi1[t][r] = b1[16*t + 4*q + r];
            bi3[t][r] = b3[16*t + 4*q + r];
            bi4[t][r] = b4[16*t + 4*q + r];
        }
    #pragma unroll
    for (int r = 0; r < 4; ++r) {
        bi2[r] = b2[4*q + r];
        bi5[r] = (q == 0 && r < 3) ? b5[r] : 0.f;
    }

    const int waveRow0 = blockIdx.x * ROWS_PER_BLOCK + w * (TPW * 16);

    // per-lane BASE pointers; per-tile offsets are wave-uniform (r is SGPR)
    const float* pp0 = pos  + (size_t)(waveRow0 + n) * 32 + 4*q;
    const float* dp0 = dir  + (size_t)(waveRow0 + n) * 3;
    float*       pD0 = outD + (size_t)(waveRow0 + n) * 16 + 4*q;
    float*       pC0 = outC + (size_t)(waveRow0 + n) * 3;   // only used by q==0 lanes

    // phase-staggered tile order: wave w starts at tile 4w, wraps mod 16
    int r = (4 * w) & 15;

    // prefetched raw inputs for first tile
    f32x4 pa = *(const f32x4*)(pp0 + r * 512);
    f32x4 pb = *(const f32x4*)(pp0 + r * 512 + 16);
    float dx = dp0[r * 48 + 0], dy = dp0[r * 48 + 1], dz = dp0[r * 48 + 2];

    for (int t = 0; t < TPW; ++t) {
        const int rn = (r + 1) & 15;   // next tile (wrap: final prefetch is in-range, unused)
        f32x4 pa2 = *(const f32x4*)(pp0 + rn * 512);
        f32x4 pb2 = *(const f32x4*)(pp0 + rn * 512 + 16);
        float dx2 = dp0[rn * 48 + 0], dy2 = dp0[rn * 48 + 1], dz2 = dp0[rn * 48 + 2];

        s8 xb = cat(pack4(pa), pack4(pb));

        // ---- L1: H^T = W1^T · X^T  (4 h-tiles, K=32) ----
        s4 hf[4];
        {
            f32x4 h0, h1, h2, h3;
            PRIO_HI();
            h0 = MFMA32(wa1[0], xb, bi1[0]);
            h1 = MFMA32(wa1[1], xb, bi1[1]);
            h2 = MFMA32(wa1[2], xb, bi1[2]);
            h3 = MFMA32(wa1[3], xb, bi1[3]);
            PRIO_LO();
            hf[0] = relu_pack4(h0); hf[1] = relu_pack4(h1);
            hf[2] = relu_pack4(h2); hf[3] = relu_pack4(h3);
        }

        // ---- L2: density (K=64 -> 2 chained MFMAs, no relu) ----
        PRIO_HI();
        f32x4 d2 = MFMA32(wa2x[0], cat(hf[0], hf[1]), bi2);
        d2 = MFMA32(wa2x[1], cat(hf[2], hf[3]), d2);
        PRIO_LO();

        // direct coalesced density store (lane(q,n): channels 4q..4q+3 of sample n)
        *(f32x4*)(pD0 + r * 256) = d2;

        // ---- SH encoding (exec-masked by q; cost = sum of branches) ----
        f32x4 shv;
        {
            const float xx = dx*dx, yy = dy*dy, zz = dz*dz;
            if (q == 0) {
                shv[0] = 0.28209479177387814f;
                shv[1] = 0.4886025119029199f * dy;
                shv[2] = 0.4886025119029199f * dz;
                shv[3] = 0.4886025119029199f * dx;
            } else if (q == 1) {
                shv[0] = 1.0925484305920792f * dx * dy;
                shv[1] = 1.0925484305920792f * dy * dz;
                shv[2] = 0.9461746957575601f * zz - 0.31539156525252f;
                shv[3] = 1.0925484305920792f * dx * dz;
            } else if (q == 2) {
                shv[0] = 0.5462742152960396f * (xx - yy);
                shv[1] = 0.5900435899266435f * dy * (3.f*xx - yy);
                shv[2] = 2.890611442640554f * dx * dy * dz;
                shv[3] = 0.4570457994644658f * dy * (5.f*zz - 1.f);
            } else {
                shv[0] = 0.3731763325901154f * dz * (5.f*zz - 3.f);
                shv[1] = 0.4570457994644658f * dx * (5.f*zz - 1.f);
                shv[2] = 1.445305721320277f  * dz * (xx - yy);
                shv[3] = 0.5900435899266435f * dx * (xx - 3.f*yy);
            }
        }
        s8 cf = cat(pack4(d2), pack4(shv));

        // ---- L3: relu(W3^T · concat^T)  (4 h-tiles, K=32) ----
        s4 gf[4];
        {
            f32x4 g0, g1, g2, g3;
            PRIO_HI();
            g0 = MFMA32(wa3[0], cf, bi3[0]);
            g1 = MFMA32(wa3[1], cf, bi3[1]);
            g2 = MFMA32(wa3[2], cf, bi3[2]);
            g3 = MFMA32(wa3[3], cf, bi3[3]);
            PRIO_LO();
            gf[0] = relu_pack4(g0); gf[1] = relu_pack4(g1);
            gf[2] = relu_pack4(g2); gf[3] = relu_pack4(g3);
        }

        // ---- L4: relu(W4^T · H3^T)  (K=64 -> 2 chained MFMAs per tt) ----
        s8 gl = cat(gf[0], gf[1]), gh = cat(gf[2], gf[3]);
        s4 ef[4];
        {
            f32x4 e0, e1, e2, e3;
            PRIO_HI();
            e0 = MFMA32(wa4x[0][0], gl, bi4[0]);
            e1 = MFMA32(wa4x[1][0], gl, bi4[1]);
            e2 = MFMA32(wa4x[2][0], gl, bi4[2]);
            e3 = MFMA32(wa4x[3][0], gl, bi4[3]);
            e0 = MFMA32(wa4x[0][1], gh, e0);
            e1 = MFMA32(wa4x[1][1], gh, e1);
            e2 = MFMA32(wa4x[2][1], gh, e2);
            e3 = MFMA32(wa4x[3][1], gh, e3);
            PRIO_LO();
            ef[0] = relu_pack4(e0); ef[1] = relu_pack4(e1);
            ef[2] = relu_pack4(e2); ef[3] = relu_pack4(e3);
        }

        // ---- L5: color (K=64 -> 2 chained MFMAs) + sigmoid ----
        PRIO_HI();
        f32x4 c5 = MFMA32(wa5x[0], cat(ef[0], ef[1]), bi5);
        c5 = MFMA32(wa5x[1], cat(ef[2], ef[3]), c5);
        PRIO_LO();

        f32x4 cv;
        cv[0] = 1.f / (1.f + __expf(-c5[0]));
        cv[1] = 1.f / (1.f + __expf(-c5[1]));
        cv[2] = 1.f / (1.f + __expf(-c5[2]));
        if (q == 0) {
            float* pc = pC0 + r * 48;
            pc[0] = cv[0];
            pc[1] = cv[1];
            pc[2] = cv[2];
        }

        r = rn;
        pa = pa2; pb = pb2; dx = dx2; dy = dy2; dz = dz2;
    }
}

extern "C" void kernel_launch(void* const* d_in, const int* in_sizes, int n_in,
                              void* d_out, int out_size, void* d_ws, size_t ws_size,
                              hipStream_t stream) {
    const float* pos = (const float*)d_in[0];
    const float* dir = (const float*)d_in[1];
    const float* W1  = (const float*)d_in[2];
    const float* b1  = (const float*)d_in[3];
    const float* W2  = (const float*)d_in[4];
    const float* b2  = (const float*)d_in[5];
    const float* W3  = (const float*)d_in[6];
    const float* b3  = (const float*)d_in[7];
    const float* W4  = (const float*)d_in[8];
    const float* b4  = (const float*)d_in[9];
    const float* W5  = (const float*)d_in[10];
    const float* b5  = (const float*)d_in[11];

    const int N = in_sizes[0] / 32;           // 1<<20
    float* outD = (float*)d_out;              // [N,16]
    float* outC = outD + (size_t)N * 16;      // [N,3]

    const int grid = N / ROWS_PER_BLOCK;      // 1024
    nerf_fused<<<grid, WAVES * 64, 0, stream>>>(pos, dir, W1, b1, W2, b2, W3, b3,
                                                W4, b4, W5, b5, outD, outC);
}

// Round 10
// 259.835 us; speedup vs baseline: 1.0261x; 1.0261x over previous
//
#include <hip/hip_runtime.h>
#include <hip/hip_bf16.h>

typedef __bf16 bf16_t;
typedef short  s4    __attribute__((ext_vector_type(4)));
typedef short  s8    __attribute__((ext_vector_type(8)));
typedef float  f32x4 __attribute__((ext_vector_type(4)));

#define TPW   16                     // tiles per wave
#define WAVES 4
#define ROWS_PER_BLOCK (WAVES * TPW * 16)   // 1024 -> grid = 1024 = 4 blocks/CU

__device__ __forceinline__ short bfs(float f) {
    return __builtin_bit_cast(short, (bf16_t)f);
}
__device__ __forceinline__ s4 pack4(f32x4 a) {
    s4 r; r[0]=bfs(a[0]); r[1]=bfs(a[1]); r[2]=bfs(a[2]); r[3]=bfs(a[3]); return r;
}
__device__ __forceinline__ s4 relu_pack4(f32x4 a) {
    s4 r;
    r[0]=bfs(fmaxf(a[0],0.f)); r[1]=bfs(fmaxf(a[1],0.f));
    r[2]=bfs(fmaxf(a[2],0.f)); r[3]=bfs(fmaxf(a[3],0.f));
    return r;
}
__device__ __forceinline__ s8 cat(s4 a, s4 b) {
    return __builtin_shufflevector(a, b, 0, 1, 2, 3, 4, 5, 6, 7);
}
// Native gfx950 shape: D = A*B + C, 16x16x32 bf16. k-map agnostic fragment
// construction (A and B gathered with the same per-(lane-group, elem) k order);
// C/D layout: col=lane&15, row=4*(lane>>4)+reg => a layer's D regs are exactly
// the next layer's B regs (after relu+pack+cat).
#define MFMA32(a,b,c) __builtin_amdgcn_mfma_f32_16x16x32_bf16(a, b, c, 0, 0, 0)

// Design ledger (measured):
//  - r1/r6: min-waves __launch_bounds__ caps -> catastrophic spills. Never cap.
//  - r4: 2-tile intra-wave ILP neutral. r8: VGPR diet to 92 / LDS weights: -8us
//    worse (DS latency in chain). r9: +8 VGPR (132) broke the 128 tier -> 4->3
//    waves/SIMD, +18% time. => all-reg weights, sequential per-layer code,
//    STAY <=128 VGPR.
//  - r7: dropping input prefetch costs ~10us. Keep the rotation.
//  - r9's tile-index stagger was a phase NO-OP (same code position across waves).
//    r10 tests phase-lock properly: per-wave s_sleep prologue offsets the CODE
//    stream by ~2048 cycles per wave (~2/3 tile); no barriers ever re-lock.
__global__ __launch_bounds__(256) void nerf_fused(
    const float* __restrict__ pos, const float* __restrict__ dir,
    const float* __restrict__ W1, const float* __restrict__ b1,
    const float* __restrict__ W2, const float* __restrict__ b2,
    const float* __restrict__ W3, const float* __restrict__ b3,
    const float* __restrict__ W4, const float* __restrict__ b4,
    const float* __restrict__ W5, const float* __restrict__ b5,
    float* __restrict__ outD, float* __restrict__ outC)
{
    const int tid  = threadIdx.x;
    const int w    = tid >> 6;
    const int lane = tid & 63;
    const int q    = lane >> 4;    // lane-group 0..3
    const int n    = lane & 15;    // A row / B col / sample-within-tile

    // ---- phase decorrelation: offset each wave's instruction stream ----
    // s_sleep N sleeps ~64*N cycles. Tile body ~3100 cycles; offsets of
    // ~2048 cycles put the block's 4 waves in different layers at any instant.
    if      (w == 1) __builtin_amdgcn_s_sleep(32);
    else if (w == 2) __builtin_amdgcn_s_sleep(64);
    else if (w == 3) __builtin_amdgcn_s_sleep(96);

    // ---------- weight A-fragments (s8 = concat of two 16-k subtiles) ----------
    s8 wa1[4], wa2x[2], wa3[4], wa4x[4][2], wa5x[2];
    #pragma unroll
    for (int t = 0; t < 4; ++t)
        #pragma unroll
        for (int h = 0; h < 2; ++h)
            #pragma unroll
            for (int i = 0; i < 4; ++i)
                wa1[t][4*h+i] = bfs(W1[(16*h + 4*q + i) * 64 + 16*t + n]);      // [32,64]
    #pragma unroll
    for (int j = 0; j < 2; ++j)
        #pragma unroll
        for (int h = 0; h < 2; ++h)
            #pragma unroll
            for (int i = 0; i < 4; ++i)
                wa2x[j][4*h+i] = bfs(W2[(16*(2*j+h) + 4*q + i) * 16 + n]);      // [64,16]
    #pragma unroll
    for (int t = 0; t < 4; ++t)
        #pragma unroll
        for (int h = 0; h < 2; ++h)
            #pragma unroll
            for (int i = 0; i < 4; ++i)
                wa3[t][4*h+i] = bfs(W3[(16*h + 4*q + i) * 64 + 16*t + n]);      // [32,64]
    #pragma unroll
    for (int t = 0; t < 4; ++t)
        #pragma unroll
        for (int j = 0; j < 2; ++j)
            #pragma unroll
            for (int h = 0; h < 2; ++h)
                #pragma unroll
                for (int i = 0; i < 4; ++i)
                    wa4x[t][j][4*h+i] = bfs(W4[(16*(2*j+h) + 4*q + i) * 64 + 16*t + n]); // [64,64]
    #pragma unroll
    for (int j = 0; j < 2; ++j)
        #pragma unroll
        for (int h = 0; h < 2; ++h)
            #pragma unroll
            for (int i = 0; i < 4; ++i)
                wa5x[j][4*h+i] = (n < 3) ? bfs(W5[(16*(2*j+h) + 4*q + i) * 3 + n])
                                         : (short)0;                             // [64,3] pad

    // ---------- bias C-initializers (channel index = 4q+r within tile t) ----------
    f32x4 bi1[4], bi3[4], bi4[4], bi2, bi5;
    #pragma unroll
    for (int t = 0; t < 4; ++t)
        #pragma unroll
        for (int r = 0; r < 4; ++r) {
            bi1[t][r] = b1[16*t + 4*q + r];
            bi3[t][r] = b3[16*t + 4*q + r];
            bi4[t][r] = b4[16*t + 4*q + r];
        }
    #pragma unroll
    for (int r = 0; r < 4; ++r) {
        bi2[r] = b2[4*q + r];
        bi5[r] = (q == 0 && r < 3) ? b5[r] : 0.f;
    }

    const int waveRow0 = blockIdx.x * ROWS_PER_BLOCK + w * (TPW * 16);

    // per-lane streaming pointers (constant per-tile strides)
    const float* pp = pos  + (size_t)(waveRow0 + n) * 32 + 4*q;
    const float* dp = dir  + (size_t)(waveRow0 + n) * 3;
    float*       pD = outD + (size_t)(waveRow0 + n) * 16 + 4*q;
    float*       pC = outC + (size_t)(waveRow0 + n) * 3;   // only used by q==0 lanes

    // prefetched raw inputs for tile 0
    f32x4 pa = *(const f32x4*)pp;
    f32x4 pb = *(const f32x4*)(pp + 16);
    float dx = dp[0];
    float dy = dp[1];
    float dz = dp[2];

    for (int t = 0; t < TPW; ++t) {
        const float* ppn = pp + ((t + 1 < TPW) ? 16 * 32 : 0);
        const float* dpn = dp + ((t + 1 < TPW) ? 16 * 3  : 0);
        f32x4 pa2 = *(const f32x4*)ppn;
        f32x4 pb2 = *(const f32x4*)(ppn + 16);
        float dx2 = dpn[0];
        float dy2 = dpn[1];
        float dz2 = dpn[2];

        // B-frag of X^T: elem 4h+i = pos[row+n][16h+4q+i]  (our k order)
        s8 xb = cat(pack4(pa), pack4(pb));

        // ---- L1: H^T = W1^T · X^T  (4 h-tiles, K=32, single MFMA each) ----
        s4 hf[4];
        #pragma unroll
        for (int tt = 0; tt < 4; ++tt) {
            f32x4 h = MFMA32(wa1[tt], xb, bi1[tt]);
            hf[tt] = relu_pack4(h);          // D regs == next-layer B regs
        }

        // ---- L2: density (K=64 -> 2 chained MFMAs, no relu) ----
        f32x4 d2 = MFMA32(wa2x[0], cat(hf[0], hf[1]), bi2);
        d2 = MFMA32(wa2x[1], cat(hf[2], hf[3]), d2);   // lane(q,n) reg r = density[s=n][c=4q+r]

        // direct coalesced density store: lane(q,n) holds channels 4q..4q+3 of
        // sample n -> contiguous 16B; the wave covers one contiguous 1 KiB segment.
        *(f32x4*)pD = d2;

        // ---- L3 B-operand: low half raw density (same regs), high half SH ----
        f32x4 shv;
        {
            const float xx = dx*dx, yy = dy*dy, zz = dz*dz;
            if (q == 0) {
                shv[0] = 0.28209479177387814f;
                shv[1] = 0.4886025119029199f * dy;
                shv[2] = 0.4886025119029199f * dz;
                shv[3] = 0.4886025119029199f * dx;
            } else if (q == 1) {
                shv[0] = 1.0925484305920792f * dx * dy;
                shv[1] = 1.0925484305920792f * dy * dz;
                shv[2] = 0.9461746957575601f * zz - 0.31539156525252f;
                shv[3] = 1.0925484305920792f * dx * dz;
            } else if (q == 2) {
                shv[0] = 0.5462742152960396f * (xx - yy);
                shv[1] = 0.5900435899266435f * dy * (3.f*xx - yy);
                shv[2] = 2.890611442640554f * dx * dy * dz;
                shv[3] = 0.4570457994644658f * dy * (5.f*zz - 1.f);
            } else {
                shv[0] = 0.3731763325901154f * dz * (5.f*zz - 3.f);
                shv[1] = 0.4570457994644658f * dx * (5.f*zz - 1.f);
                shv[2] = 1.445305721320277f  * dz * (xx - yy);
                shv[3] = 0.5900435899266435f * dx * (xx - 3.f*yy);
            }
        }
        s8 cf = cat(pack4(d2), pack4(shv));

        // ---- L3: relu(W3^T · concat^T)  (4 h-tiles, K=32, single MFMA each) ----
        s4 gf[4];
        #pragma unroll
        for (int tt = 0; tt < 4; ++tt) {
            f32x4 g = MFMA32(wa3[tt], cf, bi3[tt]);
            gf[tt] = relu_pack4(g);
        }

        // ---- L4: relu(W4^T · H3^T)  (4 h-tiles, K=64 -> 2 chained MFMAs) ----
        s8 gl = cat(gf[0], gf[1]), gh = cat(gf[2], gf[3]);
        s4 ef[4];
        #pragma unroll
        for (int tt = 0; tt < 4; ++tt) {
            f32x4 e = MFMA32(wa4x[tt][0], gl, bi4[tt]);
            e = MFMA32(wa4x[tt][1], gh, e);
            ef[tt] = relu_pack4(e);
        }

        // ---- L5: color (K=64 -> 2 chained MFMAs) + sigmoid ----
        f32x4 c5 = MFMA32(wa5x[0], cat(ef[0], ef[1]), bi5);
        c5 = MFMA32(wa5x[1], cat(ef[2], ef[3]), c5);   // valid only q==0, r<3

        // branchless sigmoid on all lanes; only q==0 lanes hold valid data + store
        f32x4 cv;
        cv[0] = 1.f / (1.f + __expf(-c5[0]));
        cv[1] = 1.f / (1.f + __expf(-c5[1]));
        cv[2] = 1.f / (1.f + __expf(-c5[2]));
        if (q == 0) {
            pC[0] = cv[0];
            pC[1] = cv[1];
            pC[2] = cv[2];
        }

        pp += 16 * 32; dp += 16 * 3; pD += 16 * 16; pC += 16 * 3;
        pa = pa2; pb = pb2; dx = dx2; dy = dy2; dz = dz2;
    }
}

extern "C" void kernel_launch(void* const* d_in, const int* in_sizes, int n_in,
                              void* d_out, int out_size, void* d_ws, size_t ws_size,
                              hipStream_t stream) {
    const float* pos = (const float*)d_in[0];
    const float* dir = (const float*)d_in[1];
    const float* W1  = (const float*)d_in[2];
    const float* b1  = (const float*)d_in[3];
    const float* W2  = (const float*)d_in[4];
    const float* b2  = (const float*)d_in[5];
    const float* W3  = (const float*)d_in[6];
    const float* b3  = (const float*)d_in[7];
    const float* W4  = (const float*)d_in[8];
    const float* b4  = (const float*)d_in[9];
    const float* W5  = (const float*)d_in[10];
    const float* b5  = (const float*)d_in[11];

    const int N = in_sizes[0] / 32;           // 1<<20
    float* outD = (float*)d_out;              // [N,16]
    float* outC = outD + (size_t)N * 16;      // [N,3]

    const int grid = N / ROWS_PER_BLOCK;      // 1024
    nerf_fused<<<grid, WAVES * 64, 0, stream>>>(pos, dir, W1, b1, W2, b2, W3, b3,
                                                W4, b4, W5, b5, outD, outC);
}

// Round 11
// 259.388 us; speedup vs baseline: 1.0279x; 1.0017x over previous
//
#include <hip/hip_runtime.h>
#include <hip/hip_bf16.h>

typedef __bf16 bf16_t;
typedef short  s4    __attribute__((ext_vector_type(4)));
typedef short  s8    __attribute__((ext_vector_type(8)));
typedef float  f32x4 __attribute__((ext_vector_type(4)));

#define TPW   16                     // tiles per wave
#define ROWS_PER_BLOCK (TPW * 16)    // 256 -> grid = 4096 single-wave blocks
                                     // = 16 blocks/CU = 4 waves/SIMD cap, fine-grained

__device__ __forceinline__ short bfs(float f) {
    return __builtin_bit_cast(short, (bf16_t)f);
}
__device__ __forceinline__ s4 pack4(f32x4 a) {
    s4 r; r[0]=bfs(a[0]); r[1]=bfs(a[1]); r[2]=bfs(a[2]); r[3]=bfs(a[3]); return r;
}
__device__ __forceinline__ s4 relu_pack4(f32x4 a) {
    s4 r;
    r[0]=bfs(fmaxf(a[0],0.f)); r[1]=bfs(fmaxf(a[1],0.f));
    r[2]=bfs(fmaxf(a[2],0.f)); r[3]=bfs(fmaxf(a[3],0.f));
    return r;
}
__device__ __forceinline__ s8 cat(s4 a, s4 b) {
    return __builtin_shufflevector(a, b, 0, 1, 2, 3, 4, 5, 6, 7);
}
// Native gfx950 shape: D = A*B + C, 16x16x32 bf16. k-map agnostic fragment
// construction (A and B gathered with the same per-(lane-group, elem) k order);
// C/D layout: col=lane&15, row=4*(lane>>4)+reg => a layer's D regs are exactly
// the next layer's B regs (after relu+pack+cat).
#define MFMA32(a,b,c) __builtin_amdgcn_mfma_f32_16x16x32_bf16(a, b, c, 0, 0, 0)

// Design ledger (measured):
//  - r1/r6: min-waves __launch_bounds__ caps -> catastrophic spills. Never cap.
//  - r4 ILP neutral; r8 LDS-weight diet worse (-8us, DS in chain); r9 VGPR 132
//    broke the 128 tier (+18% time); r10 s_sleep phase stagger flat-to-worse.
//    => all-reg weights, sequential chain, stay <=128 VGPR.
//  - r7: dropping input prefetch costs ~10us. Keep the rotation.
//  - r11 probe: OccupancyPercent has read ~18% (~6 waves/CU, ~1.5/SIMD) for every
//    256-thread-block launch despite nominal 16 waves/CU resident. Test block
//    granularity: 64-thread (single-wave) blocks, grid 4096 = 16 blocks/CU,
//    identical per-wave instruction stream.
__global__ __launch_bounds__(64) void nerf_fused(
    const float* __restrict__ pos, const float* __restrict__ dir,
    const float* __restrict__ W1, const float* __restrict__ b1,
    const float* __restrict__ W2, const float* __restrict__ b2,
    const float* __restrict__ W3, const float* __restrict__ b3,
    const float* __restrict__ W4, const float* __restrict__ b4,
    const float* __restrict__ W5, const float* __restrict__ b5,
    float* __restrict__ outD, float* __restrict__ outC)
{
    const int lane = threadIdx.x & 63;
    const int q    = lane >> 4;    // lane-group 0..3
    const int n    = lane & 15;    // A row / B col / sample-within-tile

    // ---------- weight A-fragments (s8 = concat of two 16-k subtiles) ----------
    s8 wa1[4], wa2x[2], wa3[4], wa4x[4][2], wa5x[2];
    #pragma unroll
    for (int t = 0; t < 4; ++t)
        #pragma unroll
        for (int h = 0; h < 2; ++h)
            #pragma unroll
            for (int i = 0; i < 4; ++i)
                wa1[t][4*h+i] = bfs(W1[(16*h + 4*q + i) * 64 + 16*t + n]);      // [32,64]
    #pragma unroll
    for (int j = 0; j < 2; ++j)
        #pragma unroll
        for (int h = 0; h < 2; ++h)
            #pragma unroll
            for (int i = 0; i < 4; ++i)
                wa2x[j][4*h+i] = bfs(W2[(16*(2*j+h) + 4*q + i) * 16 + n]);      // [64,16]
    #pragma unroll
    for (int t = 0; t < 4; ++t)
        #pragma unroll
        for (int h = 0; h < 2; ++h)
            #pragma unroll
            for (int i = 0; i < 4; ++i)
                wa3[t][4*h+i] = bfs(W3[(16*h + 4*q + i) * 64 + 16*t + n]);      // [32,64]
    #pragma unroll
    for (int t = 0; t < 4; ++t)
        #pragma unroll
        for (int j = 0; j < 2; ++j)
            #pragma unroll
            for (int h = 0; h < 2; ++h)
                #pragma unroll
                for (int i = 0; i < 4; ++i)
                    wa4x[t][j][4*h+i] = bfs(W4[(16*(2*j+h) + 4*q + i) * 64 + 16*t + n]); // [64,64]
    #pragma unroll
    for (int j = 0; j < 2; ++j)
        #pragma unroll
        for (int h = 0; h < 2; ++h)
            #pragma unroll
            for (int i = 0; i < 4; ++i)
                wa5x[j][4*h+i] = (n < 3) ? bfs(W5[(16*(2*j+h) + 4*q + i) * 3 + n])
                                         : (short)0;                             // [64,3] pad

    // ---------- bias C-initializers (channel index = 4q+r within tile t) ----------
    f32x4 bi1[4], bi3[4], bi4[4], bi2, bi5;
    #pragma unroll
    for (int t = 0; t < 4; ++t)
        #pragma unroll
        for (int r = 0; r < 4; ++r) {
            bi1[t][r] = b1[16*t + 4*q + r];
            bi3[t][r] = b3[16*t + 4*q + r];
            bi4[t][r] = b4[16*t + 4*q + r];
        }
    #pragma unroll
    for (int r = 0; r < 4; ++r) {
        bi2[r] = b2[4*q + r];
        bi5[r] = (q == 0 && r < 3) ? b5[r] : 0.f;
    }

    const int waveRow0 = blockIdx.x * ROWS_PER_BLOCK;

    // per-lane streaming pointers (constant per-tile strides)
    const float* pp = pos  + (size_t)(waveRow0 + n) * 32 + 4*q;
    const float* dp = dir  + (size_t)(waveRow0 + n) * 3;
    float*       pD = outD + (size_t)(waveRow0 + n) * 16 + 4*q;
    float*       pC = outC + (size_t)(waveRow0 + n) * 3;   // only used by q==0 lanes

    // prefetched raw inputs for tile 0
    f32x4 pa = *(const f32x4*)pp;
    f32x4 pb = *(const f32x4*)(pp + 16);
    float dx = dp[0];
    float dy = dp[1];
    float dz = dp[2];

    for (int t = 0; t < TPW; ++t) {
        const float* ppn = pp + ((t + 1 < TPW) ? 16 * 32 : 0);
        const float* dpn = dp + ((t + 1 < TPW) ? 16 * 3  : 0);
        f32x4 pa2 = *(const f32x4*)ppn;
        f32x4 pb2 = *(const f32x4*)(ppn + 16);
        float dx2 = dpn[0];
        float dy2 = dpn[1];
        float dz2 = dpn[2];

        // B-frag of X^T: elem 4h+i = pos[row+n][16h+4q+i]  (our k order)
        s8 xb = cat(pack4(pa), pack4(pb));

        // ---- L1: H^T = W1^T · X^T  (4 h-tiles, K=32, single MFMA each) ----
        s4 hf[4];
        #pragma unroll
        for (int tt = 0; tt < 4; ++tt) {
            f32x4 h = MFMA32(wa1[tt], xb, bi1[tt]);
            hf[tt] = relu_pack4(h);          // D regs == next-layer B regs
        }

        // ---- L2: density (K=64 -> 2 chained MFMAs, no relu) ----
        f32x4 d2 = MFMA32(wa2x[0], cat(hf[0], hf[1]), bi2);
        d2 = MFMA32(wa2x[1], cat(hf[2], hf[3]), d2);   // lane(q,n) reg r = density[s=n][c=4q+r]

        // direct coalesced density store: lane(q,n) holds channels 4q..4q+3 of
        // sample n -> contiguous 16B; the wave covers one contiguous 1 KiB segment.
        *(f32x4*)pD = d2;

        // ---- L3 B-operand: low half raw density (same regs), high half SH ----
        f32x4 shv;
        {
            const float xx = dx*dx, yy = dy*dy, zz = dz*dz;
            if (q == 0) {
                shv[0] = 0.28209479177387814f;
                shv[1] = 0.4886025119029199f * dy;
                shv[2] = 0.4886025119029199f * dz;
                shv[3] = 0.4886025119029199f * dx;
            } else if (q == 1) {
                shv[0] = 1.0925484305920792f * dx * dy;
                shv[1] = 1.0925484305920792f * dy * dz;
                shv[2] = 0.9461746957575601f * zz - 0.31539156525252f;
                shv[3] = 1.0925484305920792f * dx * dz;
            } else if (q == 2) {
                shv[0] = 0.5462742152960396f * (xx - yy);
                shv[1] = 0.5900435899266435f * dy * (3.f*xx - yy);
                shv[2] = 2.890611442640554f * dx * dy * dz;
                shv[3] = 0.4570457994644658f * dy * (5.f*zz - 1.f);
            } else {
                shv[0] = 0.3731763325901154f * dz * (5.f*zz - 3.f);
                shv[1] = 0.4570457994644658f * dx * (5.f*zz - 1.f);
                shv[2] = 1.445305721320277f  * dz * (xx - yy);
                shv[3] = 0.5900435899266435f * dx * (xx - 3.f*yy);
            }
        }
        s8 cf = cat(pack4(d2), pack4(shv));

        // ---- L3: relu(W3^T · concat^T)  (4 h-tiles, K=32, single MFMA each) ----
        s4 gf[4];
        #pragma unroll
        for (int tt = 0; tt < 4; ++tt) {
            f32x4 g = MFMA32(wa3[tt], cf, bi3[tt]);
            gf[tt] = relu_pack4(g);
        }

        // ---- L4: relu(W4^T · H3^T)  (4 h-tiles, K=64 -> 2 chained MFMAs) ----
        s8 gl = cat(gf[0], gf[1]), gh = cat(gf[2], gf[3]);
        s4 ef[4];
        #pragma unroll
        for (int tt = 0; tt < 4; ++tt) {
            f32x4 e = MFMA32(wa4x[tt][0], gl, bi4[tt]);
            e = MFMA32(wa4x[tt][1], gh, e);
            ef[tt] = relu_pack4(e);
        }

        // ---- L5: color (K=64 -> 2 chained MFMAs) + sigmoid ----
        f32x4 c5 = MFMA32(wa5x[0], cat(ef[0], ef[1]), bi5);
        c5 = MFMA32(wa5x[1], cat(ef[2], ef[3]), c5);   // valid only q==0, r<3

        // branchless sigmoid on all lanes; only q==0 lanes hold valid data + store
        f32x4 cv;
        cv[0] = 1.f / (1.f + __expf(-c5[0]));
        cv[1] = 1.f / (1.f + __expf(-c5[1]));
        cv[2] = 1.f / (1.f + __expf(-c5[2]));
        if (q == 0) {
            pC[0] = cv[0];
            pC[1] = cv[1];
            pC[2] = cv[2];
        }

        pp += 16 * 32; dp += 16 * 3; pD += 16 * 16; pC += 16 * 3;
        pa = pa2; pb = pb2; dx = dx2; dy = dy2; dz = dz2;
    }
}

extern "C" void kernel_launch(void* const* d_in, const int* in_sizes, int n_in,
                              void* d_out, int out_size, void* d_ws, size_t ws_size,
                              hipStream_t stream) {
    const float* pos = (const float*)d_in[0];
    const float* dir = (const float*)d_in[1];
    const float* W1  = (const float*)d_in[2];
    const float* b1  = (const float*)d_in[3];
    const float* W2  = (const float*)d_in[4];
    const float* b2  = (const float*)d_in[5];
    const float* W3  = (const float*)d_in[6];
    const float* b3  = (const float*)d_in[7];
    const float* W4  = (const float*)d_in[8];
    const float* b4  = (const float*)d_in[9];
    const float* W5  = (const float*)d_in[10];
    const float* b5  = (const float*)d_in[11];

    const int N = in_sizes[0] / 32;           // 1<<20
    float* outD = (float*)d_out;              // [N,16]
    float* outC = outD + (size_t)N * 16;      // [N,3]

    const int grid = N / ROWS_PER_BLOCK;      // 4096 single-wave blocks
    nerf_fused<<<grid, 64, 0, stream>>>(pos, dir, W1, b1, W2, b2, W3, b3,
                                        W4, b4, W5, b5, outD, outC);
}